// Round 3
// baseline (254.974 us; speedup 1.0000x reference)
//
#include <hip/hip_runtime.h>
#include <hip/hip_bf16.h>
#include <stdint.h>

#define B_SZ  8192
#define IN_SZ 1024
#define H_SZ  1024
#define K_BR  4
#define BR_SZ 512
#define J_SZ  2048   // IN + H (GEMM K dim)
#define BK    64     // K-step
#define NT    (J_SZ / BK)   // 32 K-tiles

#define FIX_THR 0.25f        // flag |0.5*v-1| < THR for exact fp32 recompute
#define MAXFIX  (1 << 20)    // 1M entries, 4MB

typedef __attribute__((ext_vector_type(8))) short  short8;   // 8 bf16 = 4 VGPRs
typedef __attribute__((ext_vector_type(4))) float  f32x4;

__device__ __forceinline__ unsigned short f2bf(float f) {
    union { __hip_bfloat16 b; unsigned short u; } cv;
    cv.b = __float2bfloat16(f);
    return cv.u;
}

__device__ __forceinline__ void gl_lds16(const void* g, void* l) {
    __builtin_amdgcn_global_load_lds(
        (const __attribute__((address_space(1))) void*)g,
        (__attribute__((address_space(3))) void*)l, 16, 0, 0);
}

// ---- prep 1: alpha = sigmoid(taus), biasw[h] = sum_k (1-alpha)*b[k,h]; zero cnt ----
__global__ void prep_alpha(const float* __restrict__ taus, const float* __restrict__ bvec,
                           float* __restrict__ alpha, float* __restrict__ biasw,
                           int* __restrict__ cnt) {
    int h = blockIdx.x * blockDim.x + threadIdx.x;
    if (h == 0) *cnt = 0;
    if (h >= H_SZ) return;
    float bsum = 0.f;
    for (int k = 0; k < K_BR; ++k) {
        float a = 1.f / (1.f + expf(-taus[k * H_SZ + h]));
        alpha[k * H_SZ + h] = a;
        bsum += (1.f - a) * bvec[k * H_SZ + h];
    }
    biasw[h] = bsum;
}

// ---- prep 2: Wt[h][k*512+i] = (1-alpha[k,h]) * W[k,h,i]  (bf16, B^T layout) ----
__global__ void build_wt(const float* __restrict__ W, const float* __restrict__ alpha,
                         unsigned short* __restrict__ Wt) {
    int t = blockIdx.x * 256 + threadIdx.x;
    int e0 = t * 8;
    if (e0 >= H_SZ * J_SZ) return;
    int h  = e0 >> 11;
    int j0 = e0 & 2047;
    int k  = j0 >> 9;
    int i0 = j0 & 511;
    float s = 1.f - alpha[k * H_SZ + h];
    const float* src = W + ((size_t)(k * H_SZ + h)) * BR_SZ + i0;
    union { short8 v; unsigned short u[8]; } o;
    #pragma unroll
    for (int q = 0; q < 8; ++q) o.u[q] = f2bf(s * src[q]);
    *(short8*)(Wt + (size_t)h * J_SZ + j0) = o.v;
}

// ---- prep 3: Xb[b][j] = bf16(concat(input_t, hidden)[b][j]) ----
__global__ void build_xb(const float* __restrict__ inp, const float* __restrict__ hid,
                         unsigned short* __restrict__ Xb) {
    int t = blockIdx.x * 256 + threadIdx.x;
    long long e0 = (long long)t * 8;
    if (e0 >= (long long)B_SZ * J_SZ) return;
    int b  = (int)(e0 >> 11);
    int j0 = (int)(e0 & 2047);
    const float* src = (j0 < IN_SZ) ? (inp + (size_t)b * IN_SZ + j0)
                                    : (hid + (size_t)b * H_SZ + (j0 - IN_SZ));
    union { short8 v; unsigned short u[8]; } o;
    #pragma unroll
    for (int q = 0; q < 8; ++q) o.u[q] = f2bf(src[q]);
    *(short8*)(Xb + (size_t)b * J_SZ + j0) = o.v;
}

// ---- main: 128x128 bf16 MFMA GEMM, BK=64 double-buffered 2-phase pipeline,
//      XOR-swizzled LDS (pre-swizzled global src + swizzled ds_read) ----
__global__ void gemm_spike(const unsigned short* __restrict__ Xb,
                           const unsigned short* __restrict__ Wt,
                           const float* __restrict__ alpha,
                           const float* __restrict__ biasw,
                           const float* __restrict__ bs,
                           float* __restrict__ out,
                           int* __restrict__ cnt,
                           int* __restrict__ list) {
    // [buf][row 128][k 64] bf16 = 16KB per tile per buf; A+B dbuf = 64KB
    __shared__ unsigned short As[2][128 * BK];
    __shared__ unsigned short Bs[2][128 * BK];
    const int tid  = threadIdx.x;
    const int wid  = tid >> 6;
    const int lane = tid & 63;
    const int bm0  = blockIdx.x * 128;
    const int bn0  = blockIdx.y * 128;
    const int wm   = (wid >> 1) * 64;
    const int wn   = (wid & 1) * 64;

    f32x4 acc[4][4];
    #pragma unroll
    for (int mi = 0; mi < 4; ++mi)
        #pragma unroll
        for (int ni = 0; ni < 4; ++ni)
            acc[mi][ni] = (f32x4){0.f, 0.f, 0.f, 0.f};

    const int hi = lane >> 4;     // 0..3 : selects k-slot within fragment
    const int rm = lane & 15;     // row/col within 16

    // staging geometry: per K-tile, per wave, 4 chunks of 1KB each for A and B.
    // chunk c = wid*4+p covers rows c*8 .. c*8+7 (8 rows x 128B).
    // HW writes lane l at chunkbase + l*16  ->  row = c*8 + (l>>3), slot = l&7.
    // source element = (row0+row)*J + kt + (slot ^ (row&7))*8   (swizzle involution)
    const int srow = lane >> 3;   // 0..7 row within chunk
    const int sslot = lane & 7;   // 16B slot within 128B row

    #define STAGE(kt, b)                                                          \
        {                                                                         \
            _Pragma("unroll")                                                     \
            for (int p = 0; p < 4; ++p) {                                         \
                int c    = wid * 4 + p;                                           \
                int row  = c * 8 + srow;                                          \
                int sw   = sslot ^ (row & 7);                                     \
                gl_lds16(Xb + (size_t)(bm0 + row) * J_SZ + (kt) + sw * 8,         \
                         (char*)&As[b][0] + c * 1024);                            \
                gl_lds16(Wt + (size_t)(bn0 + row) * J_SZ + (kt) + sw * 8,         \
                         (char*)&Bs[b][0] + c * 1024);                            \
            }                                                                     \
        }

    STAGE(0, 0);
    __syncthreads();

    int cur = 0;
    for (int t = 0; t < NT; ++t) {
        if (t + 1 < NT) STAGE((t + 1) * BK, cur ^ 1);

        #pragma unroll
        for (int h2 = 0; h2 < 2; ++h2) {        // k halves 0..31, 32..63
            const int s0 = h2 * 4 + hi;         // 16B slot pre-swizzle
            short8 af[4], bf[4];
            #pragma unroll
            for (int mi = 0; mi < 4; ++mi) {
                int m = wm + mi * 16 + rm;
                af[mi] = *(const short8*)((char*)&As[cur][0]
                             + m * 128 + ((s0 ^ (m & 7)) << 4));
            }
            #pragma unroll
            for (int ni = 0; ni < 4; ++ni) {
                int n = wn + ni * 16 + rm;
                bf[ni] = *(const short8*)((char*)&Bs[cur][0]
                             + n * 128 + ((s0 ^ (n & 7)) << 4));
            }
            #pragma unroll
            for (int mi = 0; mi < 4; ++mi)
                #pragma unroll
                for (int ni = 0; ni < 4; ++ni)
                    acc[mi][ni] = __builtin_amdgcn_mfma_f32_16x16x32_bf16(
                                      af[mi], bf[ni], acc[mi][ni], 0, 0, 0);
        }
        __syncthreads();   // drains vmcnt (next tile staged) + lgkm, barrier
        cur ^= 1;
    }
    #undef STAGE

    // epilogue: + biasw + sum_k alpha*branch_states, /tau, heaviside, flag borderline
    const int rr = hi * 4;            // C/D row base: (lane>>4)*4 + reg
    const int cn = rm;                // C/D col: lane&15
    #pragma unroll
    for (int ni = 0; ni < 4; ++ni) {
        int col = bn0 + wn + ni * 16 + cn;
        float bw = biasw[col];
        float a0 = alpha[0 * H_SZ + col], a1 = alpha[1 * H_SZ + col];
        float a2 = alpha[2 * H_SZ + col], a3 = alpha[3 * H_SZ + col];
        #pragma unroll
        for (int mi = 0; mi < 4; ++mi) {
            #pragma unroll
            for (int r = 0; r < 4; ++r) {
                int row = bm0 + wm + mi * 16 + rr + r;
                const float* bsp = bs + (size_t)row * (K_BR * H_SZ) + col;
                float v = acc[mi][ni][r] + bw
                        + a0 * bsp[0]        + a1 * bsp[H_SZ]
                        + a2 * bsp[2 * H_SZ] + a3 * bsp[3 * H_SZ];
                float sv = 0.5f * v - 1.0f;
                out[(size_t)row * H_SZ + col] = (sv >= 0.f) ? 1.0f : 0.0f;
                if (fabsf(sv) < FIX_THR) {
                    int slot = atomicAdd(cnt, 1);
                    if (slot < MAXFIX) list[slot] = row * H_SZ + col;
                }
            }
        }
    }
}

// ---- fixup: exact fp32 recompute of flagged (row,col), one wave each ----
__global__ void fixup(const float* __restrict__ inp, const float* __restrict__ hid,
                      const float* __restrict__ bs, const float* __restrict__ W,
                      const float* __restrict__ bvec, const float* __restrict__ alpha,
                      const int* __restrict__ cnt, const int* __restrict__ list,
                      float* __restrict__ out) {
    int wave  = (blockIdx.x * blockDim.x + threadIdx.x) >> 6;
    int lane  = threadIdx.x & 63;
    int nwave = gridDim.x * (blockDim.x >> 6);
    int n = *cnt;
    if (n > MAXFIX) n = MAXFIX;
    for (int it = wave; it < n; it += nwave) {
        int idx = list[it];
        int row = idx >> 10, col = idx & 1023;
        float a[K_BR];
        #pragma unroll
        for (int k = 0; k < K_BR; ++k) a[k] = alpha[k * H_SZ + col];
        float acc = 0.f;
        for (int j = lane; j < J_SZ; j += 64) {
            int k = j >> 9, i = j & 511;
            float x = (j < IN_SZ) ? inp[(size_t)row * IN_SZ + j]
                                  : hid[(size_t)row * H_SZ + (j - IN_SZ)];
            float w = W[((size_t)(k * H_SZ + col)) * BR_SZ + i];
            acc += (1.f - a[k]) * x * w;
        }
        #pragma unroll
        for (int off = 32; off; off >>= 1) acc += __shfl_xor(acc, off, 64);
        if (lane == 0) {
            float tot = acc;
            #pragma unroll
            for (int k = 0; k < K_BR; ++k)
                tot += (1.f - a[k]) * bvec[k * H_SZ + col]
                     + a[k] * bs[(size_t)row * (K_BR * H_SZ) + k * H_SZ + col];
            out[(size_t)row * H_SZ + col] = (0.5f * tot - 1.f >= 0.f) ? 1.f : 0.f;
        }
    }
}

// ---- fallback if workspace too small: direct fp32 (slow but correct) ----
__global__ void naive_kernel(const float* __restrict__ inp, const float* __restrict__ hid,
                             const float* __restrict__ bs, const float* __restrict__ W,
                             const float* __restrict__ bvec, const float* __restrict__ taus,
                             float* __restrict__ out) {
    int idx = blockIdx.x * 256 + threadIdx.x;
    if (idx >= B_SZ * H_SZ) return;
    int b = idx >> 10, h = idx & 1023;
    float tot = 0.f;
    for (int k = 0; k < K_BR; ++k) {
        const float* x = (k < 2) ? (inp + (size_t)b * IN_SZ + k * BR_SZ)
                                 : (hid + (size_t)b * H_SZ + (k - 2) * BR_SZ);
        const float* w = W + ((size_t)k * H_SZ + h) * BR_SZ;
        float d = 0.f;
        for (int i = 0; i < BR_SZ; ++i) d += x[i] * w[i];
        d += bvec[k * H_SZ + h];
        float a = 1.f / (1.f + expf(-taus[k * H_SZ + h]));
        tot += a * bs[(size_t)b * (K_BR * H_SZ) + k * H_SZ + h] + (1.f - a) * d;
    }
    out[idx] = (0.5f * tot - 1.f >= 0.f) ? 1.f : 0.f;
}

extern "C" void kernel_launch(void* const* d_in, const int* in_sizes, int n_in,
                              void* d_out, int out_size, void* d_ws, size_t ws_size,
                              hipStream_t stream) {
    const float* input_t = (const float*)d_in[0];
    const float* hidden  = (const float*)d_in[1];
    const float* bs      = (const float*)d_in[2];
    const float* W       = (const float*)d_in[3];
    const float* bvec    = (const float*)d_in[4];
    const float* taus    = (const float*)d_in[5];
    float* out = (float*)d_out;

    const size_t ALPHA_OFF = 0;
    const size_t BIAS_OFF  = 16 * 1024;
    const size_t CNT_OFF   = 32 * 1024;
    const size_t LIST_OFF  = 48 * 1024;
    const size_t WT_OFF    = LIST_OFF + (size_t)MAXFIX * 4;      // +4MB
    const size_t XB_OFF    = WT_OFF + (size_t)H_SZ * J_SZ * 2;   // +4MB
    const size_t WS_NEED   = XB_OFF + (size_t)B_SZ * J_SZ * 2;   // +32MB

    if (ws_size < WS_NEED) {
        naive_kernel<<<(B_SZ * H_SZ + 255) / 256, 256, 0, stream>>>(
            input_t, hidden, bs, W, bvec, taus, out);
        return;
    }

    float*          alphaw = (float*)((char*)d_ws + ALPHA_OFF);
    float*          biasw  = (float*)((char*)d_ws + BIAS_OFF);
    int*            cnt    = (int*)((char*)d_ws + CNT_OFF);
    int*            list   = (int*)((char*)d_ws + LIST_OFF);
    unsigned short* Wt     = (unsigned short*)((char*)d_ws + WT_OFF);
    unsigned short* Xb     = (unsigned short*)((char*)d_ws + XB_OFF);

    prep_alpha<<<4, 256, 0, stream>>>(taus, bvec, alphaw, biasw, cnt);
    build_wt<<<(H_SZ * J_SZ / 8 + 255) / 256, 256, 0, stream>>>(W, alphaw, Wt);
    build_xb<<<(B_SZ * J_SZ / 8 + 255) / 256, 256, 0, stream>>>(input_t, hidden, Xb);
    gemm_spike<<<dim3(B_SZ / 128, H_SZ / 128), 256, 0, stream>>>(
        Xb, Wt, alphaw, biasw, bs, out, cnt, list);
    fixup<<<128, 256, 0, stream>>>(input_t, hidden, bs, W, bvec, alphaw, cnt, list, out);
}

// Round 4
// 221.381 us; speedup vs baseline: 1.1517x; 1.1517x over previous
//
#include <hip/hip_runtime.h>
#include <hip/hip_bf16.h>
#include <stdint.h>

#define B_SZ  8192
#define IN_SZ 1024
#define H_SZ  1024
#define K_BR  4
#define BR_SZ 512
#define J_SZ  2048   // IN + H (GEMM K dim)
#define BK    64     // K-step
#define NT    (J_SZ / BK)   // 32 K-tiles

#define FIX_THR 0.25f        // flag |0.5*v-1| < THR for exact fp32 recompute
#define MAXFIX  (1 << 20)    // 1M entries, 4MB

typedef __attribute__((ext_vector_type(8))) short  short8;   // 8 bf16 = 4 VGPRs
typedef __attribute__((ext_vector_type(4))) float  f32x4;

__device__ __forceinline__ unsigned short f2bf(float f) {
    union { __hip_bfloat16 b; unsigned short u; } cv;
    cv.b = __float2bfloat16(f);
    return cv.u;
}
__device__ __forceinline__ float bf2f(unsigned short u) {
    union { float f; unsigned int i; } cv;
    cv.i = ((unsigned int)u) << 16;
    return cv.f;
}

__device__ __forceinline__ void gl_lds16(const void* g, void* l) {
    __builtin_amdgcn_global_load_lds(
        (const __attribute__((address_space(1))) void*)g,
        (__attribute__((address_space(3))) void*)l, 16, 0, 0);
}

// ---- prep: alpha = sigmoid(taus), biasw[h] = sum_k (1-alpha)*b[k,h]; zero cnt ----
__global__ void prep_alpha(const float* __restrict__ taus, const float* __restrict__ bvec,
                           float* __restrict__ alpha, float* __restrict__ biasw,
                           int* __restrict__ cnt) {
    int h = blockIdx.x * blockDim.x + threadIdx.x;
    if (h == 0) *cnt = 0;
    if (h >= H_SZ) return;
    float bsum = 0.f;
    for (int k = 0; k < K_BR; ++k) {
        float a = 1.f / (1.f + expf(-taus[k * H_SZ + h]));
        alpha[k * H_SZ + h] = a;
        bsum += (1.f - a) * bvec[k * H_SZ + h];
    }
    biasw[h] = bsum;
}

// ---- prep 2: Wt[h][k*512+i] = (1-sigmoid(taus[k,h])) * W[k,h,i]  (bf16, B^T) ----
__global__ void build_wt(const float* __restrict__ W, const float* __restrict__ taus,
                         unsigned short* __restrict__ Wt) {
    int t = blockIdx.x * 256 + threadIdx.x;
    int e0 = t * 8;
    if (e0 >= H_SZ * J_SZ) return;
    int h  = e0 >> 11;
    int j0 = e0 & 2047;
    int k  = j0 >> 9;
    int i0 = j0 & 511;
    float a = 1.f / (1.f + expf(-taus[k * H_SZ + h]));
    float s = 1.f - a;
    const float* src = W + ((size_t)(k * H_SZ + h)) * BR_SZ + i0;
    union { short8 v; unsigned short u[8]; } o;
    #pragma unroll
    for (int q = 0; q < 8; ++q) o.u[q] = f2bf(s * src[q]);
    *(short8*)(Wt + (size_t)h * J_SZ + j0) = o.v;
}

// ---- prep 3: Xb[b][j] = bf16(concat(input_t, hidden)[b][j]) ----
__global__ void build_xb(const float* __restrict__ inp, const float* __restrict__ hid,
                         unsigned short* __restrict__ Xb) {
    int t = blockIdx.x * 256 + threadIdx.x;
    long long e0 = (long long)t * 8;
    if (e0 >= (long long)B_SZ * J_SZ) return;
    int b  = (int)(e0 >> 11);
    int j0 = (int)(e0 & 2047);
    const float* src = (j0 < IN_SZ) ? (inp + (size_t)b * IN_SZ + j0)
                                    : (hid + (size_t)b * H_SZ + (j0 - IN_SZ));
    union { short8 v; unsigned short u[8]; } o;
    #pragma unroll
    for (int q = 0; q < 8; ++q) o.u[q] = f2bf(src[q]);
    *(short8*)(Xb + (size_t)b * J_SZ + j0) = o.v;
}

// ---- main GEMM: 128x128 tile, 8 waves (2x4), BK=64 dbuf, swizzled LDS.
//      Writes tc = GEMM result (bf16). No epilogue here. ----
__global__ void __launch_bounds__(512, 4)
gemm_tc(const unsigned short* __restrict__ Xb,
        const unsigned short* __restrict__ Wt,
        unsigned short* __restrict__ tc) {
    __shared__ unsigned short As[2][128 * BK];   // 16KB per buf
    __shared__ unsigned short Bs[2][128 * BK];
    const int tid  = threadIdx.x;
    const int wid  = tid >> 6;          // 0..7
    const int lane = tid & 63;
    const int bm0  = blockIdx.x * 128;
    const int bn0  = blockIdx.y * 128;
    const int wm   = (wid >> 2) * 64;   // 2 wave-rows of 64
    const int wn   = (wid & 3) * 32;    // 4 wave-cols of 32

    f32x4 acc[4][2];
    #pragma unroll
    for (int mi = 0; mi < 4; ++mi)
        #pragma unroll
        for (int ni = 0; ni < 2; ++ni)
            acc[mi][ni] = (f32x4){0.f, 0.f, 0.f, 0.f};

    const int hi = lane >> 4;     // 0..3 k-slot selector
    const int rm = lane & 15;

    // staging: 16 chunks of 1KB per array; wave wid owns chunks 2*wid, 2*wid+1.
    // chunk c covers rows c*8..c*8+7; HW writes lane l at base + l*16.
    const int srow  = lane >> 3;  // row within chunk
    const int sslot = lane & 7;   // 16B slot within 128B row

    #define STAGE(kt, b)                                                          \
        {                                                                         \
            _Pragma("unroll")                                                     \
            for (int p = 0; p < 2; ++p) {                                         \
                int c    = wid * 2 + p;                                           \
                int row  = c * 8 + srow;                                          \
                int sw   = sslot ^ (row & 7);                                     \
                gl_lds16(Xb + (size_t)(bm0 + row) * J_SZ + (kt) + sw * 8,         \
                         (char*)&As[b][0] + c * 1024);                            \
                gl_lds16(Wt + (size_t)(bn0 + row) * J_SZ + (kt) + sw * 8,         \
                         (char*)&Bs[b][0] + c * 1024);                            \
            }                                                                     \
        }

    STAGE(0, 0);
    __syncthreads();

    int cur = 0;
    for (int t = 0; t < NT; ++t) {
        if (t + 1 < NT) STAGE((t + 1) * BK, cur ^ 1);

        #pragma unroll
        for (int h2 = 0; h2 < 2; ++h2) {        // k halves 0..31, 32..63
            const int s0 = h2 * 4 + hi;         // 16B slot pre-swizzle
            short8 af[4], bf[2];
            #pragma unroll
            for (int mi = 0; mi < 4; ++mi) {
                int m = wm + mi * 16 + rm;
                af[mi] = *(const short8*)((char*)&As[cur][0]
                             + m * 128 + ((s0 ^ (m & 7)) << 4));
            }
            #pragma unroll
            for (int ni = 0; ni < 2; ++ni) {
                int n = wn + ni * 16 + rm;
                bf[ni] = *(const short8*)((char*)&Bs[cur][0]
                             + n * 128 + ((s0 ^ (n & 7)) << 4));
            }
            #pragma unroll
            for (int mi = 0; mi < 4; ++mi)
                #pragma unroll
                for (int ni = 0; ni < 2; ++ni)
                    acc[mi][ni] = __builtin_amdgcn_mfma_f32_16x16x32_bf16(
                                      af[mi], bf[ni], acc[mi][ni], 0, 0, 0);
        }
        __syncthreads();
        cur ^= 1;
    }
    #undef STAGE

    // write tc as bf16 (C/D map: col=lane&15, row=(lane>>4)*4+reg)
    const int rr = hi * 4;
    #pragma unroll
    for (int ni = 0; ni < 2; ++ni) {
        int col = bn0 + wn + ni * 16 + rm;
        #pragma unroll
        for (int mi = 0; mi < 4; ++mi) {
            #pragma unroll
            for (int r = 0; r < 4; ++r) {
                int row = bm0 + wm + mi * 16 + rr + r;
                tc[(size_t)row * H_SZ + col] = f2bf(acc[mi][ni][r]);
            }
        }
    }
}

// ---- streaming epilogue: v = tc + biasw + sum_k alpha*bs; spike; flag ----
__global__ void spike_fuse(const unsigned short* __restrict__ tc,
                           const float* __restrict__ bs,
                           const float* __restrict__ alpha,
                           const float* __restrict__ biasw,
                           float* __restrict__ out,
                           int* __restrict__ cnt,
                           int* __restrict__ list) {
    const int NE4 = B_SZ * H_SZ / 4;
    for (int e4 = blockIdx.x * blockDim.x + threadIdx.x; e4 < NE4;
         e4 += gridDim.x * blockDim.x) {
        int row = e4 >> 8;              // 256 float4 per row
        int c   = (e4 & 255) << 2;      // col base
        // load 4 bf16 tc values
        union { unsigned long long u64; unsigned short u[4]; } t4;
        t4.u64 = *(const unsigned long long*)(tc + (size_t)row * H_SZ + c);
        float4 bw = *(const float4*)(biasw + c);
        float v[4];
        #pragma unroll
        for (int j = 0; j < 4; ++j) v[j] = bf2f(t4.u[j]);
        v[0] += bw.x; v[1] += bw.y; v[2] += bw.z; v[3] += bw.w;
        const float* bsr = bs + (size_t)row * (K_BR * H_SZ) + c;
        #pragma unroll
        for (int k = 0; k < K_BR; ++k) {
            float4 a4 = *(const float4*)(alpha + k * H_SZ + c);
            float4 b4 = *(const float4*)(bsr + k * H_SZ);
            v[0] += a4.x * b4.x; v[1] += a4.y * b4.y;
            v[2] += a4.z * b4.z; v[3] += a4.w * b4.w;
        }
        float4 o;
        float sv[4];
        #pragma unroll
        for (int j = 0; j < 4; ++j) sv[j] = 0.5f * v[j] - 1.0f;
        o.x = (sv[0] >= 0.f) ? 1.f : 0.f;
        o.y = (sv[1] >= 0.f) ? 1.f : 0.f;
        o.z = (sv[2] >= 0.f) ? 1.f : 0.f;
        o.w = (sv[3] >= 0.f) ? 1.f : 0.f;
        *(float4*)(out + (size_t)row * H_SZ + c) = o;
        #pragma unroll
        for (int j = 0; j < 4; ++j) {
            if (fabsf(sv[j]) < FIX_THR) {
                int slot = atomicAdd(cnt, 1);
                if (slot < MAXFIX) list[slot] = row * H_SZ + c + j;
            }
        }
    }
}

// ---- fixup: exact fp32 recompute of flagged (row,col), one wave each ----
__global__ void fixup(const float* __restrict__ inp, const float* __restrict__ hid,
                      const float* __restrict__ bs, const float* __restrict__ W,
                      const float* __restrict__ bvec, const float* __restrict__ alpha,
                      const int* __restrict__ cnt, const int* __restrict__ list,
                      float* __restrict__ out) {
    int wave  = (blockIdx.x * blockDim.x + threadIdx.x) >> 6;
    int lane  = threadIdx.x & 63;
    int nwave = gridDim.x * (blockDim.x >> 6);
    int n = *cnt;
    if (n > MAXFIX) n = MAXFIX;
    for (int it = wave; it < n; it += nwave) {
        int idx = list[it];
        int row = idx >> 10, col = idx & 1023;
        float a[K_BR];
        #pragma unroll
        for (int k = 0; k < K_BR; ++k) a[k] = alpha[k * H_SZ + col];
        float acc = 0.f;
        for (int j = lane; j < J_SZ; j += 64) {
            int k = j >> 9, i = j & 511;
            float x = (j < IN_SZ) ? inp[(size_t)row * IN_SZ + j]
                                  : hid[(size_t)row * H_SZ + (j - IN_SZ)];
            float w = W[((size_t)(k * H_SZ + col)) * BR_SZ + i];
            acc += (1.f - a[k]) * x * w;
        }
        #pragma unroll
        for (int off = 32; off; off >>= 1) acc += __shfl_xor(acc, off, 64);
        if (lane == 0) {
            float tot = acc;
            #pragma unroll
            for (int k = 0; k < K_BR; ++k)
                tot += (1.f - a[k]) * bvec[k * H_SZ + col]
                     + a[k] * bs[(size_t)row * (K_BR * H_SZ) + k * H_SZ + col];
            out[(size_t)row * H_SZ + col] = (0.5f * tot - 1.f >= 0.f) ? 1.f : 0.f;
        }
    }
}

// ---- fallback if workspace too small: direct fp32 (slow but correct) ----
__global__ void naive_kernel(const float* __restrict__ inp, const float* __restrict__ hid,
                             const float* __restrict__ bs, const float* __restrict__ W,
                             const float* __restrict__ bvec, const float* __restrict__ taus,
                             float* __restrict__ out) {
    int idx = blockIdx.x * 256 + threadIdx.x;
    if (idx >= B_SZ * H_SZ) return;
    int b = idx >> 10, h = idx & 1023;
    float tot = 0.f;
    for (int k = 0; k < K_BR; ++k) {
        const float* x = (k < 2) ? (inp + (size_t)b * IN_SZ + k * BR_SZ)
                                 : (hid + (size_t)b * H_SZ + (k - 2) * BR_SZ);
        const float* w = W + ((size_t)k * H_SZ + h) * BR_SZ;
        float d = 0.f;
        for (int i = 0; i < BR_SZ; ++i) d += x[i] * w[i];
        d += bvec[k * H_SZ + h];
        float a = 1.f / (1.f + expf(-taus[k * H_SZ + h]));
        tot += a * bs[(size_t)b * (K_BR * H_SZ) + k * H_SZ + h] + (1.f - a) * d;
    }
    out[idx] = (0.5f * tot - 1.f >= 0.f) ? 1.f : 0.f;
}

extern "C" void kernel_launch(void* const* d_in, const int* in_sizes, int n_in,
                              void* d_out, int out_size, void* d_ws, size_t ws_size,
                              hipStream_t stream) {
    const float* input_t = (const float*)d_in[0];
    const float* hidden  = (const float*)d_in[1];
    const float* bs      = (const float*)d_in[2];
    const float* W       = (const float*)d_in[3];
    const float* bvec    = (const float*)d_in[4];
    const float* taus    = (const float*)d_in[5];
    float* out = (float*)d_out;

    const size_t ALPHA_OFF = 0;
    const size_t BIAS_OFF  = 16 * 1024;
    const size_t CNT_OFF   = 32 * 1024;
    const size_t LIST_OFF  = 48 * 1024;
    const size_t WT_OFF    = LIST_OFF + (size_t)MAXFIX * 4;      // +4MB
    const size_t XB_OFF    = WT_OFF + (size_t)H_SZ * J_SZ * 2;   // +4MB
    const size_t TC_OFF    = XB_OFF + (size_t)B_SZ * J_SZ * 2;   // +32MB
    const size_t WS_NEED   = TC_OFF + (size_t)B_SZ * H_SZ * 2;   // +16MB

    if (ws_size < WS_NEED) {
        naive_kernel<<<(B_SZ * H_SZ + 255) / 256, 256, 0, stream>>>(
            input_t, hidden, bs, W, bvec, taus, out);
        return;
    }

    float*          alphaw = (float*)((char*)d_ws + ALPHA_OFF);
    float*          biasw  = (float*)((char*)d_ws + BIAS_OFF);
    int*            cnt    = (int*)((char*)d_ws + CNT_OFF);
    int*            list   = (int*)((char*)d_ws + LIST_OFF);
    unsigned short* Wt     = (unsigned short*)((char*)d_ws + WT_OFF);
    unsigned short* Xb     = (unsigned short*)((char*)d_ws + XB_OFF);
    unsigned short* tc     = (unsigned short*)((char*)d_ws + TC_OFF);

    prep_alpha<<<4, 256, 0, stream>>>(taus, bvec, alphaw, biasw, cnt);
    build_wt<<<(H_SZ * J_SZ / 8 + 255) / 256, 256, 0, stream>>>(W, taus, Wt);
    build_xb<<<(B_SZ * J_SZ / 8 + 255) / 256, 256, 0, stream>>>(input_t, hidden, Xb);
    gemm_tc<<<dim3(B_SZ / 128, H_SZ / 128), 512, 0, stream>>>(Xb, Wt, tc);
    spike_fuse<<<2048, 256, 0, stream>>>(tc, bs, alphaw, biasw, out, cnt, list);
    fixup<<<128, 256, 0, stream>>>(input_t, hidden, bs, W, bvec, alphaw, cnt, list, out);
}

// Round 5
// 99.710 us; speedup vs baseline: 2.5572x; 2.2202x over previous
//
#include <hip/hip_runtime.h>
#include <hip/hip_bf16.h>
#include <stdint.h>

#define B_SZ  8192
#define IN_SZ 1024
#define H_SZ  1024
#define K_BR  4
#define BR_SZ 512
#define J_SZ  2048   // IN + H (GEMM K dim)
#define BK    64     // K-step
#define NT    (J_SZ / BK)   // 32 K-tiles

#define FIX_THR 0.08f        // flag |0.5*v-1| < THR for exact fp32 recompute
#define MAXFIX  (1 << 20)    // 1M entries, 4MB

typedef __attribute__((ext_vector_type(8))) short  short8;   // 8 bf16 = 4 VGPRs
typedef __attribute__((ext_vector_type(4))) float  f32x4;

__device__ __forceinline__ unsigned short f2bf(float f) {
    union { __hip_bfloat16 b; unsigned short u; } cv;
    cv.b = __float2bfloat16(f);
    return cv.u;
}
__device__ __forceinline__ float bf2f(unsigned short u) {
    union { float f; unsigned int i; } cv;
    cv.i = ((unsigned int)u) << 16;
    return cv.f;
}

__device__ __forceinline__ void gl_lds16(const void* g, void* l) {
    __builtin_amdgcn_global_load_lds(
        (const __attribute__((address_space(1))) void*)g,
        (__attribute__((address_space(3))) void*)l, 16, 0, 0);
}

// ---- prep: alpha = sigmoid(taus), biasw[h] = sum_k (1-alpha)*b[k,h]; zero cnt ----
__global__ void prep_alpha(const float* __restrict__ taus, const float* __restrict__ bvec,
                           float* __restrict__ alpha, float* __restrict__ biasw,
                           int* __restrict__ cnt) {
    int h = blockIdx.x * blockDim.x + threadIdx.x;
    if (h == 0) *cnt = 0;
    if (h >= H_SZ) return;
    float bsum = 0.f;
    for (int k = 0; k < K_BR; ++k) {
        float a = 1.f / (1.f + expf(-taus[k * H_SZ + h]));
        alpha[k * H_SZ + h] = a;
        bsum += (1.f - a) * bvec[k * H_SZ + h];
    }
    biasw[h] = bsum;
}

// ---- prep 2: Wt[h][k*512+i] = (1-sigmoid(taus[k,h])) * W[k,h,i]  (bf16, B^T) ----
__global__ void build_wt(const float* __restrict__ W, const float* __restrict__ taus,
                         unsigned short* __restrict__ Wt) {
    int t = blockIdx.x * 256 + threadIdx.x;
    int e0 = t * 8;
    if (e0 >= H_SZ * J_SZ) return;
    int h  = e0 >> 11;
    int j0 = e0 & 2047;
    int k  = j0 >> 9;
    int i0 = j0 & 511;
    float a = 1.f / (1.f + expf(-taus[k * H_SZ + h]));
    float s = 1.f - a;
    const float* src = W + ((size_t)(k * H_SZ + h)) * BR_SZ + i0;
    union { short8 v; unsigned short u[8]; } o;
    #pragma unroll
    for (int q = 0; q < 8; ++q) o.u[q] = f2bf(s * src[q]);
    *(short8*)(Wt + (size_t)h * J_SZ + j0) = o.v;
}

// ---- prep 3: Xb[b][j] = bf16(concat(input_t, hidden)[b][j]) ----
__global__ void build_xb(const float* __restrict__ inp, const float* __restrict__ hid,
                         unsigned short* __restrict__ Xb) {
    int t = blockIdx.x * 256 + threadIdx.x;
    long long e0 = (long long)t * 8;
    if (e0 >= (long long)B_SZ * J_SZ) return;
    int b  = (int)(e0 >> 11);
    int j0 = (int)(e0 & 2047);
    const float* src = (j0 < IN_SZ) ? (inp + (size_t)b * IN_SZ + j0)
                                    : (hid + (size_t)b * H_SZ + (j0 - IN_SZ));
    union { short8 v; unsigned short u[8]; } o;
    #pragma unroll
    for (int q = 0; q < 8; ++q) o.u[q] = f2bf(src[q]);
    *(short8*)(Xb + (size_t)b * J_SZ + j0) = o.v;
}

// ---- main GEMM: 128x128 tile, 8 waves (2x4), BK=64 dbuf, swizzled LDS.
//      Writes tc = GEMM result (bf16). No epilogue here. ----
__global__ void __launch_bounds__(512, 4)
gemm_tc(const unsigned short* __restrict__ Xb,
        const unsigned short* __restrict__ Wt,
        unsigned short* __restrict__ tc) {
    __shared__ unsigned short As[2][128 * BK];   // 16KB per buf
    __shared__ unsigned short Bs[2][128 * BK];
    const int tid  = threadIdx.x;
    const int wid  = tid >> 6;          // 0..7
    const int lane = tid & 63;
    const int bm0  = blockIdx.x * 128;
    const int bn0  = blockIdx.y * 128;
    const int wm   = (wid >> 2) * 64;   // 2 wave-rows of 64
    const int wn   = (wid & 3) * 32;    // 4 wave-cols of 32

    f32x4 acc[4][2];
    #pragma unroll
    for (int mi = 0; mi < 4; ++mi)
        #pragma unroll
        for (int ni = 0; ni < 2; ++ni)
            acc[mi][ni] = (f32x4){0.f, 0.f, 0.f, 0.f};

    const int hi = lane >> 4;     // 0..3 k-slot selector
    const int rm = lane & 15;

    const int srow  = lane >> 3;  // row within chunk
    const int sslot = lane & 7;   // 16B slot within 128B row

    #define STAGE(kt, b)                                                          \
        {                                                                         \
            _Pragma("unroll")                                                     \
            for (int p = 0; p < 2; ++p) {                                         \
                int c    = wid * 2 + p;                                           \
                int row  = c * 8 + srow;                                          \
                int sw   = sslot ^ (row & 7);                                     \
                gl_lds16(Xb + (size_t)(bm0 + row) * J_SZ + (kt) + sw * 8,         \
                         (char*)&As[b][0] + c * 1024);                            \
                gl_lds16(Wt + (size_t)(bn0 + row) * J_SZ + (kt) + sw * 8,         \
                         (char*)&Bs[b][0] + c * 1024);                            \
            }                                                                     \
        }

    STAGE(0, 0);
    __syncthreads();

    int cur = 0;
    for (int t = 0; t < NT; ++t) {
        if (t + 1 < NT) STAGE((t + 1) * BK, cur ^ 1);

        #pragma unroll
        for (int h2 = 0; h2 < 2; ++h2) {        // k halves 0..31, 32..63
            const int s0 = h2 * 4 + hi;         // 16B slot pre-swizzle
            short8 af[4], bf[2];
            #pragma unroll
            for (int mi = 0; mi < 4; ++mi) {
                int m = wm + mi * 16 + rm;
                af[mi] = *(const short8*)((char*)&As[cur][0]
                             + m * 128 + ((s0 ^ (m & 7)) << 4));
            }
            #pragma unroll
            for (int ni = 0; ni < 2; ++ni) {
                int n = wn + ni * 16 + rm;
                bf[ni] = *(const short8*)((char*)&Bs[cur][0]
                             + n * 128 + ((s0 ^ (n & 7)) << 4));
            }
            #pragma unroll
            for (int mi = 0; mi < 4; ++mi)
                #pragma unroll
                for (int ni = 0; ni < 2; ++ni)
                    acc[mi][ni] = __builtin_amdgcn_mfma_f32_16x16x32_bf16(
                                      af[mi], bf[ni], acc[mi][ni], 0, 0, 0);
        }
        __syncthreads();
        cur ^= 1;
    }
    #undef STAGE

    // write tc as bf16 (C/D map: col=lane&15, row=(lane>>4)*4+reg)
    const int rr = hi * 4;
    #pragma unroll
    for (int ni = 0; ni < 2; ++ni) {
        int col = bn0 + wn + ni * 16 + rm;
        #pragma unroll
        for (int mi = 0; mi < 4; ++mi) {
            #pragma unroll
            for (int r = 0; r < 4; ++r) {
                int row = bm0 + wm + mi * 16 + rr + r;
                tc[(size_t)row * H_SZ + col] = f2bf(acc[mi][ni][r]);
            }
        }
    }
}

// ---- streaming epilogue: v = tc + biasw + sum_k alpha*bs; spike; flag ----
__global__ void spike_fuse(const unsigned short* __restrict__ tc,
                           const float* __restrict__ bs,
                           const float* __restrict__ alpha,
                           const float* __restrict__ biasw,
                           float* __restrict__ out,
                           int* __restrict__ cnt,
                           int* __restrict__ list) {
    const int NE4 = B_SZ * H_SZ / 4;
    for (int e4 = blockIdx.x * blockDim.x + threadIdx.x; e4 < NE4;
         e4 += gridDim.x * blockDim.x) {
        int row = e4 >> 8;              // 256 float4 per row
        int c   = (e4 & 255) << 2;      // col base
        union { unsigned long long u64; unsigned short u[4]; } t4;
        t4.u64 = *(const unsigned long long*)(tc + (size_t)row * H_SZ + c);
        float4 bw = *(const float4*)(biasw + c);
        float v[4];
        #pragma unroll
        for (int j = 0; j < 4; ++j) v[j] = bf2f(t4.u[j]);
        v[0] += bw.x; v[1] += bw.y; v[2] += bw.z; v[3] += bw.w;
        const float* bsr = bs + (size_t)row * (K_BR * H_SZ) + c;
        #pragma unroll
        for (int k = 0; k < K_BR; ++k) {
            float4 a4 = *(const float4*)(alpha + k * H_SZ + c);
            float4 b4 = *(const float4*)(bsr + k * H_SZ);
            v[0] += a4.x * b4.x; v[1] += a4.y * b4.y;
            v[2] += a4.z * b4.z; v[3] += a4.w * b4.w;
        }
        float4 o;
        float sv[4];
        #pragma unroll
        for (int j = 0; j < 4; ++j) sv[j] = 0.5f * v[j] - 1.0f;
        o.x = (sv[0] >= 0.f) ? 1.f : 0.f;
        o.y = (sv[1] >= 0.f) ? 1.f : 0.f;
        o.z = (sv[2] >= 0.f) ? 1.f : 0.f;
        o.w = (sv[3] >= 0.f) ? 1.f : 0.f;
        *(float4*)(out + (size_t)row * H_SZ + c) = o;
        #pragma unroll
        for (int j = 0; j < 4; ++j) {
            if (fabsf(sv[j]) < FIX_THR) {
                int slot = atomicAdd(cnt, 1);
                if (slot < MAXFIX) list[slot] = row * H_SZ + c + j;
            }
        }
    }
}

// ---- fixup: exact fp32 recompute of flagged (row,col), one wave each.
//      Fully unrolled float4 loads: 16 outstanding loads per item. ----
__global__ void fixup(const float* __restrict__ inp, const float* __restrict__ hid,
                      const float* __restrict__ bs, const float* __restrict__ W,
                      const float* __restrict__ bvec, const float* __restrict__ alpha,
                      const int* __restrict__ cnt, const int* __restrict__ list,
                      float* __restrict__ out) {
    int wave  = (blockIdx.x * blockDim.x + threadIdx.x) >> 6;
    int lane  = threadIdx.x & 63;
    int nwave = gridDim.x * (blockDim.x >> 6);
    int n = *cnt;
    if (n > MAXFIX) n = MAXFIX;
    for (int it = wave; it < n; it += nwave) {
        int idx = list[it];
        int row = idx >> 10, col = idx & 1023;
        float a[K_BR];
        #pragma unroll
        for (int k = 0; k < K_BR; ++k) a[k] = alpha[k * H_SZ + col];
        const float* xi = inp + (size_t)row * IN_SZ;
        const float* xh = hid + (size_t)row * H_SZ;
        // lane covers j = p*256 + lane*4 + {0..3}, p = 0..7  (J = 2048)
        float4 xv[8], wv[8];
        #pragma unroll
        for (int p = 0; p < 8; ++p) {
            int j = p * 256 + lane * 4;            // branch k = p>>1 (uniform)
            xv[p] = (p < 4) ? *(const float4*)(xi + j)
                            : *(const float4*)(xh + j - IN_SZ);
            int i = (p & 1) * 256 + lane * 4;      // j & 511
            wv[p] = *(const float4*)(W + ((size_t)((p >> 1) * H_SZ + col)) * BR_SZ + i);
        }
        float acc = 0.f;
        #pragma unroll
        for (int p = 0; p < 8; ++p) {
            float s = 1.f - a[p >> 1];
            acc += s * (xv[p].x * wv[p].x + xv[p].y * wv[p].y
                      + xv[p].z * wv[p].z + xv[p].w * wv[p].w);
        }
        #pragma unroll
        for (int off = 32; off; off >>= 1) acc += __shfl_xor(acc, off, 64);
        if (lane == 0) {
            float tot = acc;
            #pragma unroll
            for (int k = 0; k < K_BR; ++k)
                tot += (1.f - a[k]) * bvec[k * H_SZ + col]
                     + a[k] * bs[(size_t)row * (K_BR * H_SZ) + k * H_SZ + col];
            out[(size_t)row * H_SZ + col] = (0.5f * tot - 1.f >= 0.f) ? 1.f : 0.f;
        }
    }
}

// ---- fallback if workspace too small: direct fp32 (slow but correct) ----
__global__ void naive_kernel(const float* __restrict__ inp, const float* __restrict__ hid,
                             const float* __restrict__ bs, const float* __restrict__ W,
                             const float* __restrict__ bvec, const float* __restrict__ taus,
                             float* __restrict__ out) {
    int idx = blockIdx.x * 256 + threadIdx.x;
    if (idx >= B_SZ * H_SZ) return;
    int b = idx >> 10, h = idx & 1023;
    float tot = 0.f;
    for (int k = 0; k < K_BR; ++k) {
        const float* x = (k < 2) ? (inp + (size_t)b * IN_SZ + k * BR_SZ)
                                 : (hid + (size_t)b * H_SZ + (k - 2) * BR_SZ);
        const float* w = W + ((size_t)k * H_SZ + h) * BR_SZ;
        float d = 0.f;
        for (int i = 0; i < BR_SZ; ++i) d += x[i] * w[i];
        d += bvec[k * H_SZ + h];
        float a = 1.f / (1.f + expf(-taus[k * H_SZ + h]));
        tot += a * bs[(size_t)b * (K_BR * H_SZ) + k * H_SZ + h] + (1.f - a) * d;
    }
    out[idx] = (0.5f * tot - 1.f >= 0.f) ? 1.f : 0.f;
}

extern "C" void kernel_launch(void* const* d_in, const int* in_sizes, int n_in,
                              void* d_out, int out_size, void* d_ws, size_t ws_size,
                              hipStream_t stream) {
    const float* input_t = (const float*)d_in[0];
    const float* hidden  = (const float*)d_in[1];
    const float* bs      = (const float*)d_in[2];
    const float* W       = (const float*)d_in[3];
    const float* bvec    = (const float*)d_in[4];
    const float* taus    = (const float*)d_in[5];
    float* out = (float*)d_out;

    const size_t ALPHA_OFF = 0;
    const size_t BIAS_OFF  = 16 * 1024;
    const size_t CNT_OFF   = 32 * 1024;
    const size_t LIST_OFF  = 48 * 1024;
    const size_t WT_OFF    = LIST_OFF + (size_t)MAXFIX * 4;      // +4MB
    const size_t XB_OFF    = WT_OFF + (size_t)H_SZ * J_SZ * 2;   // +4MB
    const size_t TC_OFF    = XB_OFF + (size_t)B_SZ * J_SZ * 2;   // +32MB
    const size_t WS_NEED   = TC_OFF + (size_t)B_SZ * H_SZ * 2;   // +16MB

    if (ws_size < WS_NEED) {
        naive_kernel<<<(B_SZ * H_SZ + 255) / 256, 256, 0, stream>>>(
            input_t, hidden, bs, W, bvec, taus, out);
        return;
    }

    float*          alphaw = (float*)((char*)d_ws + ALPHA_OFF);
    float*          biasw  = (float*)((char*)d_ws + BIAS_OFF);
    int*            cnt    = (int*)((char*)d_ws + CNT_OFF);
    int*            list   = (int*)((char*)d_ws + LIST_OFF);
    unsigned short* Wt     = (unsigned short*)((char*)d_ws + WT_OFF);
    unsigned short* Xb     = (unsigned short*)((char*)d_ws + XB_OFF);
    unsigned short* tc     = (unsigned short*)((char*)d_ws + TC_OFF);

    prep_alpha<<<4, 256, 0, stream>>>(taus, bvec, alphaw, biasw, cnt);
    build_wt<<<(H_SZ * J_SZ / 8 + 255) / 256, 256, 0, stream>>>(W, taus, Wt);
    build_xb<<<(B_SZ * J_SZ / 8 + 255) / 256, 256, 0, stream>>>(input_t, hidden, Xb);
    gemm_tc<<<dim3(B_SZ / 128, H_SZ / 128), 512, 0, stream>>>(Xb, Wt, tc);
    spike_fuse<<<2048, 256, 0, stream>>>(tc, bs, alphaw, biasw, out, cnt, list);
    fixup<<<2048, 256, 0, stream>>>(input_t, hidden, bs, W, bvec, alphaw, cnt, list, out);
}